// Round 9
// baseline (107.712 us; speedup 1.0000x reference)
//
#include <hip/hip_runtime.h>
#include <hip/hip_bf16.h>

// BATCH=512, INPUT_SIZE=64, ALPHA_DIM=64
// out[b,:] = log( M_0 ... M_62 p ).  SINGLE fused kernel, 256 blocks x 512
// threads (129 KB LDS => exactly 1 block/CU => all 256 blocks co-resident,
// so a device-scope atomic grid barrier is deadlock-free).
//  Phase A (blocks 0..15): E[t][v] = sigma_v(theta_t) col-scaled by
//    softmax(u_t), bf16, straight into LDS. Each t stored in exactly ONE
//    orientation (odd position -> col-store for A-operand reads, even ->
//    row-store for B-operand reads), XOR-swizzled (byte ^= (row&7)<<4).
//  Phase B (blocks 0..15, 8 waves): 248 group products (15 quads x 16
//    variants + 8 triple variants), depth-2 MFMA per product with the
//    R7-validated role-0 LDS round-trip + lane^32 B-rebuild; C3 stored to
//    MqC (global) in bf16 chain layout: P[a][j] at (j>>3)*512 + a*8 + (j&7).
//  Grid barrier (memset-zeroed counter + threadfence/atomicAdd/acquire spin).
//  Phase C (all blocks): per batch (2 per block) the R8-validated 16-step
//    matvec chain, 4 waves/batch, 2-step-ahead register prefetch.

#define NSTEP 63

typedef __attribute__((ext_vector_type(8)))  short short8;
typedef __attribute__((ext_vector_type(16))) float f32x16;

union U8 { short8 v; unsigned u[4]; unsigned short s[8]; };

static __device__ __forceinline__ unsigned short bf16b(float f) {
  union { __hip_bfloat16 h; unsigned short u; } cv;
  cv.h = __float2bfloat16(f);
  return cv.u;
}
static __device__ __forceinline__ unsigned pack2(float a, float b) {
  return (unsigned)bf16b(a) | ((unsigned)bf16b(b) << 16);
}
static __device__ __forceinline__ float bfcvt(unsigned short s) {
  return __uint_as_float((unsigned)s << 16);
}

// ---------------- MFMA helpers (R5-R8 validated byte patterns) -------------
static __device__ __forceinline__ void mm64(const short8 A[4][2],
                                            const short8 B[4][2],
                                            f32x16 C[2][2]) {
  #pragma unroll
  for (int ti = 0; ti < 2; ++ti)
    #pragma unroll
    for (int j = 0; j < 2; ++j)
      #pragma unroll
      for (int r = 0; r < 16; ++r) C[ti][j][r] = 0.0f;
  #pragma unroll
  for (int kc = 0; kc < 4; ++kc)
    #pragma unroll
    for (int j = 0; j < 2; ++j)
      #pragma unroll
      for (int ti = 0; ti < 2; ++ti)
        C[ti][j] = __builtin_amdgcn_mfma_f32_32x32x16_bf16(
            A[kc][ti], B[kc][j], C[ti][j], 0, 0, 0);
}

// all LDS tiles use XOR swizzle: byteoff = (row*128 + col*2) ^ ((row&7)<<4)
static __device__ __forceinline__ void loadA_lds(short8 A[4][2],
                                                 const char* base,
                                                 int lo, int hi) {
  #pragma unroll
  for (int kc = 0; kc < 4; ++kc)
    #pragma unroll
    for (int ti = 0; ti < 2; ++ti) {
      int m = 32 * ti + lo;
      unsigned byteoff = ((unsigned)(m * 128 + (16 * kc + 8 * hi) * 2)) ^
                         ((unsigned)(m & 7) << 4);
      A[kc][ti] = *reinterpret_cast<const short8*>(base + byteoff);
    }
}
static __device__ __forceinline__ void loadB_lds(short8 B[4][2],
                                                 const char* base,
                                                 int lo, int hi) {
  #pragma unroll
  for (int kc = 0; kc < 4; ++kc)
    #pragma unroll
    for (int j = 0; j < 2; ++j) {
      int n = 32 * j + lo;
      unsigned byteoff = ((unsigned)(n * 128 + (16 * kc + 8 * hi) * 2)) ^
                         ((unsigned)(n & 7) << 4);
      B[kc][j] = *reinterpret_cast<const short8*>(base + byteoff);
    }
}
static __device__ __forceinline__ void store_role0(const f32x16 C[2][2],
                                                   char* base, int lo, int hi) {
  #pragma unroll
  for (int ti = 0; ti < 2; ++ti)
    #pragma unroll
    for (int j = 0; j < 2; ++j)
      #pragma unroll
      for (int r = 0; r < 16; ++r) {
        int m = 32 * ti + (r & 3) + 8 * (r >> 2) + 4 * hi;
        int n = 32 * j + lo;
        unsigned byteoff =
            ((unsigned)(m * 128 + n * 2)) ^ ((unsigned)(m & 7) << 4);
        *reinterpret_cast<unsigned short*>(base + byteoff) = bf16b(C[ti][j][r]);
      }
}
static __device__ __forceinline__ void rebuildB(const f32x16 C[2][2],
                                                short8 B[4][2], int hi) {
  #pragma unroll
  for (int kc = 0; kc < 4; ++kc) {
    int Me = 2 * kc, Mo = 2 * kc + 1;
    int tie = Me >> 2, me = Me & 3;
    int tio = Mo >> 2, mo = Mo & 3;
    #pragma unroll
    for (int j = 0; j < 2; ++j) {
      unsigned pe0 = pack2(C[tie][j][4 * me + 0], C[tie][j][4 * me + 1]);
      unsigned pe1 = pack2(C[tie][j][4 * me + 2], C[tie][j][4 * me + 3]);
      unsigned po0 = pack2(C[tio][j][4 * mo + 0], C[tio][j][4 * mo + 1]);
      unsigned po1 = pack2(C[tio][j][4 * mo + 2], C[tio][j][4 * mo + 3]);
      unsigned s0 = hi ? pe0 : po0;
      unsigned s1 = hi ? pe1 : po1;
      unsigned r0 = (unsigned)__shfl_xor((int)s0, 32);
      unsigned r1 = (unsigned)__shfl_xor((int)s1, 32);
      U8 f;
      f.u[0] = hi ? r0 : pe0;
      f.u[1] = hi ? r1 : pe1;
      f.u[2] = hi ? po0 : r0;
      f.u[3] = hi ? po1 : r1;
      B[kc][j] = f.v;
    }
  }
}

// ---------------- fused kernel ----------------
__global__ __launch_bounds__(512, 2) void fused_kernel(
    const float* __restrict__ x, const float* __restrict__ theta,
    const float* __restrict__ ulpa, unsigned short* __restrict__ MqC,
    unsigned* __restrict__ bar, float* __restrict__ out) {
  __shared__ union {
    struct {
      unsigned short E[8][4096];   // 64 KB: slot[i*2+v], one orientation each
      char role[8][8192];          // 64 KB: per-wave role-0 buffer
      float pa[4][64];             // softmax(ulpa) per t
    } ab;
    struct { float ubuf[2][2][64]; } c;  // phase C ping-pong, per half-block
  } sm;

  int bid = blockIdx.x;           // 0..255
  int tid = threadIdx.x;          // 0..511
  int wid = tid >> 6, lane = tid & 63, lo = lane & 31, hi = lane >> 5;

  // ================= phase A+B: blocks 0..15 build the table =================
  if (bid < 16) {
    int g = bid;
    int nt = (g < 15) ? 4 : 3;
    int t0 = 4 * g;
    int ti_ = wid >> 1, h = wid & 1;   // wave (ti_,h): t = t0+ti_, row-half h

    if (ti_ < nt) {
      int t = t0 + ti_;
      float uu = ulpa[t * 64 + lane];
      float mx = uu;
      #pragma unroll
      for (int o = 32; o >= 1; o >>= 1) mx = fmaxf(mx, __shfl_xor(mx, o));
      float e = __expf(uu - mx);
      float ssum = e;
      #pragma unroll
      for (int o = 32; o >= 1; o >>= 1) ssum += __shfl_xor(ssum, o);
      if (h == 0) sm.ab.pa[ti_][lane] = e / ssum;
    }
    __syncthreads();

    if (ti_ < nt) {
      int t = t0 + ti_;
      // odd position -> col-store (A-operand); even -> row-store (B-operand)
      bool colstore = (g < 15) ? ((ti_ & 1) != 0) : (ti_ == 2);
      const float4* th4 = (const float4*)(theta + t * 4096);
      unsigned short* S1 = sm.ab.E[ti_ * 2 + 1];
      unsigned short* S0 = sm.ab.E[ti_ * 2 + 0];
      #pragma unroll
      for (int k = 0; k < 8; ++k) {
        int f = k * 64 + lane;            // float4 id within this half
        int m = 32 * h + (f >> 4);
        int c0 = (f & 15) * 4;
        float4 tv = th4[m * 16 + (c0 >> 2)];
        float s0 = 1.0f / (1.0f + __expf(-tv.x));
        float s1 = 1.0f / (1.0f + __expf(-tv.y));
        float s2 = 1.0f / (1.0f + __expf(-tv.z));
        float s3 = 1.0f / (1.0f + __expf(-tv.w));
        float p0 = sm.ab.pa[ti_][c0 + 0], p1 = sm.ab.pa[ti_][c0 + 1];
        float p2 = sm.ab.pa[ti_][c0 + 2], p3 = sm.ab.pa[ti_][c0 + 3];
        float a0 = s0 * p0, a1 = s1 * p1, a2 = s2 * p2, a3 = s3 * p3;
        float b0 = (1.0f - s0) * p0, b1 = (1.0f - s1) * p1;
        float b2 = (1.0f - s2) * p2, b3 = (1.0f - s3) * p3;
        if (!colstore) {
          unsigned off = ((unsigned)(m * 128 + c0 * 2)) ^
                         ((unsigned)(m & 7) << 4);
          *reinterpret_cast<uint2*>(reinterpret_cast<char*>(S1) + off) =
              make_uint2(pack2(a0, a1), pack2(a2, a3));
          *reinterpret_cast<uint2*>(reinterpret_cast<char*>(S0) + off) =
              make_uint2(pack2(b0, b1), pack2(b2, b3));
        } else {
          float av[4] = {a0, a1, a2, a3}, bv[4] = {b0, b1, b2, b3};
          #pragma unroll
          for (int e = 0; e < 4; ++e) {
            int c = c0 + e;
            unsigned off = ((unsigned)(c * 128 + m * 2)) ^
                           ((unsigned)(c & 7) << 4);
            *reinterpret_cast<unsigned short*>(
                reinterpret_cast<char*>(S1) + off) = bf16b(av[e]);
            *reinterpret_cast<unsigned short*>(
                reinterpret_cast<char*>(S0) + off) = bf16b(bv[e]);
          }
        }
      }
    }
    __syncthreads();

    // ---- phase B: products. blocks 0-14: v = 2*wid, 2*wid+1; block 15: wid.
    int nv = (g < 15) ? 2 : ((wid < 8) ? 1 : 0);
    for (int pv = 0; pv < nv; ++pv) {
      int v = (g < 15) ? (2 * wid + pv) : wid;
      short8 A[4][2], B[4][2];
      f32x16 C1[2][2], C2[2][2], C3[2][2];
      char* role = sm.ab.role[wid];
      if (g < 15) {
        int b0 = v & 1, b1 = (v >> 1) & 1, b2 = (v >> 2) & 1, b3 = (v >> 3) & 1;
        loadA_lds(A, (char*)sm.ab.E[3 * 2 + b3], lo, hi);   // E3^T (col-stored)
        loadB_lds(B, (char*)sm.ab.E[2 * 2 + b2], lo, hi);   // E2^T (row-stored)
        mm64(A, B, C1);                                     // (E2E3)^T
        loadA_lds(A, (char*)sm.ab.E[1 * 2 + b1], lo, hi);   // E1^T
        loadB_lds(B, (char*)sm.ab.E[0 * 2 + b0], lo, hi);   // E0^T
        mm64(A, B, C2);                                     // (E0E1)^T
        store_role0(C1, role, lo, hi);  // single wave: ds ops program-ordered
        loadA_lds(A, role, lo, hi);
        rebuildB(C2, B, hi);
        mm64(A, B, C3);                                     // (E0..E3)^T
      } else {
        int b0 = v & 1, b1 = (v >> 1) & 1, b2 = (v >> 2) & 1;
        loadA_lds(A, (char*)sm.ab.E[2 * 2 + b2], lo, hi);   // E62^T (col)
        loadB_lds(B, (char*)sm.ab.E[1 * 2 + b1], lo, hi);   // E61^T (row)
        mm64(A, B, C1);                                     // (E61E62)^T
        store_role0(C1, role, lo, hi);
        loadA_lds(A, role, lo, hi);
        loadB_lds(B, (char*)sm.ab.E[0 * 2 + b0], lo, hi);   // E60^T (row)
        mm64(A, B, C3);                                     // (E60..E62)^T
      }
      int bid_p = (g < 15) ? (g * 16 + v) : (240 + v);
      unsigned short* outp = MqC + (size_t)bid_p * 4096;
      #pragma unroll
      for (int ti = 0; ti < 2; ++ti)
        #pragma unroll
        for (int j = 0; j < 2; ++j)
          #pragma unroll
          for (int r = 0; r < 16; ++r) {
            int m = 32 * ti + (r & 3) + 8 * (r >> 2) + 4 * hi;  // PT row=P col
            int n = 32 * j + lo;                                // PT col=P row
            outp[(m >> 3) * 512 + n * 8 + (m & 7)] = bf16b(C3[ti][j][r]);
          }
    }
  }

  // ================= grid barrier (all 256 blocks co-resident) ==============
  __syncthreads();
  if (tid == 0) {
    __threadfence();                     // release MqC stores (device scope)
    atomicAdd(bar, 1u);
    while (__hip_atomic_load(bar, __ATOMIC_ACQUIRE,
                             __HIP_MEMORY_SCOPE_AGENT) < 256u) {
      __builtin_amdgcn_s_sleep(8);
    }
    __threadfence();
  }
  __syncthreads();

  // ================= phase C: chain, 2 batches per block =====================
  {
    int half = wid >> 2;                // 0/1: which batch of this block
    int w = wid & 3;                    // wave within the batch's 4-wave team
    int bb = bid * 2 + half;            // 0..511
    int l = lane;
    int al = l & 15;
    int q = l >> 4;
    int a = 16 * w + al;
    float (*UB)[64] = sm.c.ubuf[half];

    unsigned long long mask = __ballot(x[bb * 64 + l] != 0.0f);

    float th = theta[63 * 4096 + l * 64];
    float sg = 1.0f / (1.0f + __expf(-th));
    float pvv = ((mask >> 63) & 1ull) ? sg : (1.0f - sg);
    if (w == 0) UB[0][l] = pvv;
    __syncthreads();

#define GIDX(g) ((g) < 15 ? (g) * 16 + (int)((mask >> (4 * (g))) & 15ull) \
                          : 240 + (int)((mask >> 60) & 7ull))

    short8 qa[2], qb[2], qc[2];

#define PRE(REG, PG)                                                        \
    {                                                                       \
      const unsigned short* Pb =                                            \
          MqC + (size_t)GIDX(PG) * 4096 + (q * 1024 + a * 8);               \
      REG[0] = *reinterpret_cast<const short8*>(Pb);                        \
      REG[1] = *reinterpret_cast<const short8*>(Pb + 512);                  \
    }

    float rscale = 1.0f, acc = 0.0f;

#define STEP(QREG, PG, PREG, CUR, DO_RS, LAST)                              \
    {                                                                       \
      if ((PG) >= 0) PRE(PREG, PG);                                         \
      const float* uc = UB[CUR];                                            \
      float4 u0 = *(const float4*)&uc[16 * q + 0];                          \
      float4 u1 = *(const float4*)&uc[16 * q + 4];                          \
      float4 u2 = *(const float4*)&uc[16 * q + 8];                          \
      float4 u3 = *(const float4*)&uc[16 * q + 12];                         \
      U8 f0, f1;                                                            \
      f0.v = QREG[0]; f1.v = QREG[1];                                       \
      float s0 = 0.f, s1 = 0.f, s2 = 0.f, s3 = 0.f;                         \
      s0 = fmaf(bfcvt(f0.s[0]), u0.x, s0);                                  \
      s1 = fmaf(bfcvt(f0.s[1]), u0.y, s1);                                  \
      s2 = fmaf(bfcvt(f0.s[2]), u0.z, s2);                                  \
      s3 = fmaf(bfcvt(f0.s[3]), u0.w, s3);                                  \
      s0 = fmaf(bfcvt(f0.s[4]), u1.x, s0);                                  \
      s1 = fmaf(bfcvt(f0.s[5]), u1.y, s1);                                  \
      s2 = fmaf(bfcvt(f0.s[6]), u1.z, s2);                                  \
      s3 = fmaf(bfcvt(f0.s[7]), u1.w, s3);                                  \
      s0 = fmaf(bfcvt(f1.s[0]), u2.x, s0);                                  \
      s1 = fmaf(bfcvt(f1.s[1]), u2.y, s1);                                  \
      s2 = fmaf(bfcvt(f1.s[2]), u2.z, s2);                                  \
      s3 = fmaf(bfcvt(f1.s[3]), u2.w, s3);                                  \
      s0 = fmaf(bfcvt(f1.s[4]), u3.x, s0);                                  \
      s1 = fmaf(bfcvt(f1.s[5]), u3.y, s1);                                  \
      s2 = fmaf(bfcvt(f1.s[6]), u3.z, s2);                                  \
      s3 = fmaf(bfcvt(f1.s[7]), u3.w, s3);                                  \
      float s = (s0 + s1) + (s2 + s3);                                      \
      s += __shfl_xor(s, 16);                                               \
      s += __shfl_xor(s, 32);                                               \
      if (DO_RS) s *= rscale;                                               \
      if (LAST) {                                                           \
        if (q == 0) out[bb * 64 + a] = logf(s) + acc;                       \
      } else {                                                              \
        if (q == 0) UB[(CUR) ^ 1][a] = s;                                   \
        __syncthreads();                                                    \
      }                                                                     \
    }

    PRE(qa, 15);
    PRE(qb, 14);

    STEP(qa, 13, qc, 0, 0, 0);   // g=15
    STEP(qb, 12, qa, 1, 0, 0);   // g=14
    STEP(qc, 11, qb, 0, 0, 0);   // g=13
    STEP(qa, 10, qc, 1, 0, 0);   // g=12
    STEP(qb,  9, qa, 0, 0, 0);   // g=11
    STEP(qc,  8, qb, 1, 0, 0);   // g=10
    STEP(qa,  7, qc, 0, 0, 0);   // g=9
    STEP(qb,  6, qa, 1, 0, 0);   // g=8  -> u in UB[0]

    {  // renorm (same placement as R7/R8)
      float uv = UB[0][l];
      float m = uv;
      #pragma unroll
      for (int o = 32; o >= 1; o >>= 1) m = fmaxf(m, __shfl_xor(m, o));
      rscale = 1.0f / m;
      acc = __logf(m);
    }

    STEP(qc,  5, qb, 0, 1, 0);   // g=7, applies rscale
    STEP(qa,  4, qc, 1, 0, 0);   // g=6
    STEP(qb,  3, qa, 0, 0, 0);   // g=5
    STEP(qc,  2, qb, 1, 0, 0);   // g=4
    STEP(qa,  1, qc, 0, 0, 0);   // g=3
    STEP(qb,  0, qa, 1, 0, 0);   // g=2
    STEP(qc, -1, qb, 0, 0, 0);   // g=1
    STEP(qa, -1, qb, 1, 0, 1);   // g=0, write out

#undef STEP
#undef PRE
#undef GIDX
  }
}

extern "C" void kernel_launch(void* const* d_in, const int* in_sizes, int n_in,
                              void* d_out, int out_size, void* d_ws, size_t ws_size,
                              hipStream_t stream) {
  const float* x     = (const float*)d_in[0];  // (512, 64)
  const float* theta = (const float*)d_in[1];  // (1, 64, 64, 64)
  const float* ulpa  = (const float*)d_in[2];  // (1, 63, 1, 64)
  float* out = (float*)d_out;                  // (512, 64, 1)

  unsigned short* MqC = (unsigned short*)d_ws;           // 248*4096 bf16 (2 MB)
  unsigned* bar = (unsigned*)((char*)d_ws + (size_t)248 * 4096 * 2);

  hipMemsetAsync(bar, 0, 64, stream);
  hipLaunchKernelGGL(fused_kernel, dim3(256), dim3(512), 0, stream,
                     x, theta, ulpa, MqC, bar, out);
}

// Round 10
// 85.066 us; speedup vs baseline: 1.2662x; 1.2662x over previous
//
#include <hip/hip_runtime.h>
#include <hip/hip_bf16.h>

// BATCH=512, INPUT_SIZE=64, ALPHA_DIM=64
// out[b,:] = log( M_0 ... M_62 p ).  Two kernels (no grid barrier — R9's
// fused barrier version measured 65us of spin/coherence stall; reverted):
//  table_kernel (16 blocks x 512): R9's validated phases A+B. E[t][v] built
//    straight into LDS (one orientation per t: odd position col-stored for
//    A-operand reads, even row-stored for B-operand reads, XOR-swizzled),
//    then 8 waves compute the 248 group products (depth-2 MFMA, role-0 LDS
//    round-trip + lane^32 B-rebuild) into MqC in bf16 chain layout:
//    P[a][j] at (j>>3)*512 + a*8 + (j&7).
//  chain_kernel (512 blocks x 256): R8-validated 16-step matvec chain,
//    4 waves/batch, 2-step-ahead register prefetch, one renorm.

#define NSTEP 63

typedef __attribute__((ext_vector_type(8)))  short short8;
typedef __attribute__((ext_vector_type(16))) float f32x16;

union U8 { short8 v; unsigned u[4]; unsigned short s[8]; };

static __device__ __forceinline__ unsigned short bf16b(float f) {
  union { __hip_bfloat16 h; unsigned short u; } cv;
  cv.h = __float2bfloat16(f);
  return cv.u;
}
static __device__ __forceinline__ unsigned pack2(float a, float b) {
  return (unsigned)bf16b(a) | ((unsigned)bf16b(b) << 16);
}
static __device__ __forceinline__ float bfcvt(unsigned short s) {
  return __uint_as_float((unsigned)s << 16);
}

// ---------------- MFMA helpers (R5-R9 validated byte patterns) -------------
static __device__ __forceinline__ void mm64(const short8 A[4][2],
                                            const short8 B[4][2],
                                            f32x16 C[2][2]) {
  #pragma unroll
  for (int ti = 0; ti < 2; ++ti)
    #pragma unroll
    for (int j = 0; j < 2; ++j)
      #pragma unroll
      for (int r = 0; r < 16; ++r) C[ti][j][r] = 0.0f;
  #pragma unroll
  for (int kc = 0; kc < 4; ++kc)
    #pragma unroll
    for (int j = 0; j < 2; ++j)
      #pragma unroll
      for (int ti = 0; ti < 2; ++ti)
        C[ti][j] = __builtin_amdgcn_mfma_f32_32x32x16_bf16(
            A[kc][ti], B[kc][j], C[ti][j], 0, 0, 0);
}

// all LDS tiles use XOR swizzle: byteoff = (row*128 + col*2) ^ ((row&7)<<4)
static __device__ __forceinline__ void loadA_lds(short8 A[4][2],
                                                 const char* base,
                                                 int lo, int hi) {
  #pragma unroll
  for (int kc = 0; kc < 4; ++kc)
    #pragma unroll
    for (int ti = 0; ti < 2; ++ti) {
      int m = 32 * ti + lo;
      unsigned byteoff = ((unsigned)(m * 128 + (16 * kc + 8 * hi) * 2)) ^
                         ((unsigned)(m & 7) << 4);
      A[kc][ti] = *reinterpret_cast<const short8*>(base + byteoff);
    }
}
static __device__ __forceinline__ void loadB_lds(short8 B[4][2],
                                                 const char* base,
                                                 int lo, int hi) {
  #pragma unroll
  for (int kc = 0; kc < 4; ++kc)
    #pragma unroll
    for (int j = 0; j < 2; ++j) {
      int n = 32 * j + lo;
      unsigned byteoff = ((unsigned)(n * 128 + (16 * kc + 8 * hi) * 2)) ^
                         ((unsigned)(n & 7) << 4);
      B[kc][j] = *reinterpret_cast<const short8*>(base + byteoff);
    }
}
static __device__ __forceinline__ void store_role0(const f32x16 C[2][2],
                                                   char* base, int lo, int hi) {
  #pragma unroll
  for (int ti = 0; ti < 2; ++ti)
    #pragma unroll
    for (int j = 0; j < 2; ++j)
      #pragma unroll
      for (int r = 0; r < 16; ++r) {
        int m = 32 * ti + (r & 3) + 8 * (r >> 2) + 4 * hi;
        int n = 32 * j + lo;
        unsigned byteoff =
            ((unsigned)(m * 128 + n * 2)) ^ ((unsigned)(m & 7) << 4);
        *reinterpret_cast<unsigned short*>(base + byteoff) = bf16b(C[ti][j][r]);
      }
}
static __device__ __forceinline__ void rebuildB(const f32x16 C[2][2],
                                                short8 B[4][2], int hi) {
  #pragma unroll
  for (int kc = 0; kc < 4; ++kc) {
    int Me = 2 * kc, Mo = 2 * kc + 1;
    int tie = Me >> 2, me = Me & 3;
    int tio = Mo >> 2, mo = Mo & 3;
    #pragma unroll
    for (int j = 0; j < 2; ++j) {
      unsigned pe0 = pack2(C[tie][j][4 * me + 0], C[tie][j][4 * me + 1]);
      unsigned pe1 = pack2(C[tie][j][4 * me + 2], C[tie][j][4 * me + 3]);
      unsigned po0 = pack2(C[tio][j][4 * mo + 0], C[tio][j][4 * mo + 1]);
      unsigned po1 = pack2(C[tio][j][4 * mo + 2], C[tio][j][4 * mo + 3]);
      unsigned s0 = hi ? pe0 : po0;
      unsigned s1 = hi ? pe1 : po1;
      unsigned r0 = (unsigned)__shfl_xor((int)s0, 32);
      unsigned r1 = (unsigned)__shfl_xor((int)s1, 32);
      U8 f;
      f.u[0] = hi ? r0 : pe0;
      f.u[1] = hi ? r1 : pe1;
      f.u[2] = hi ? po0 : r0;
      f.u[3] = hi ? po1 : r1;
      B[kc][j] = f.v;
    }
  }
}

// ---------------- table_kernel: E in LDS + 248 group products --------------
__global__ __launch_bounds__(512) void table_kernel(
    const float* __restrict__ theta, const float* __restrict__ ulpa,
    unsigned short* __restrict__ MqC) {
  __shared__ __align__(16) unsigned short E[8][4096];   // 64 KB
  __shared__ __align__(16) char role[8][8192];          // 64 KB
  __shared__ float pa[4][64];

  int g = blockIdx.x;             // 0..15
  int tid = threadIdx.x;          // 0..511
  int wid = tid >> 6, lane = tid & 63, lo = lane & 31, hi = lane >> 5;

  int nt = (g < 15) ? 4 : 3;
  int t0 = 4 * g;
  int ti_ = wid >> 1, h = wid & 1;   // wave (ti_,h): t = t0+ti_, row-half h

  // ---- phase A: softmax(ulpa) + E tiles straight into LDS
  if (ti_ < nt) {
    int t = t0 + ti_;
    float uu = ulpa[t * 64 + lane];
    float mx = uu;
    #pragma unroll
    for (int o = 32; o >= 1; o >>= 1) mx = fmaxf(mx, __shfl_xor(mx, o));
    float e = __expf(uu - mx);
    float ssum = e;
    #pragma unroll
    for (int o = 32; o >= 1; o >>= 1) ssum += __shfl_xor(ssum, o);
    if (h == 0) pa[ti_][lane] = e / ssum;
  }
  __syncthreads();

  if (ti_ < nt) {
    int t = t0 + ti_;
    // odd position -> col-store (A-operand); even -> row-store (B-operand)
    bool colstore = (g < 15) ? ((ti_ & 1) != 0) : (ti_ == 2);
    const float4* th4 = (const float4*)(theta + t * 4096);
    unsigned short* S1 = E[ti_ * 2 + 1];
    unsigned short* S0 = E[ti_ * 2 + 0];
    #pragma unroll
    for (int k = 0; k < 8; ++k) {
      int f = k * 64 + lane;            // float4 id within this half
      int m = 32 * h + (f >> 4);
      int c0 = (f & 15) * 4;
      float4 tv = th4[m * 16 + (c0 >> 2)];
      float s0 = 1.0f / (1.0f + __expf(-tv.x));
      float s1 = 1.0f / (1.0f + __expf(-tv.y));
      float s2 = 1.0f / (1.0f + __expf(-tv.z));
      float s3 = 1.0f / (1.0f + __expf(-tv.w));
      float p0 = pa[ti_][c0 + 0], p1 = pa[ti_][c0 + 1];
      float p2 = pa[ti_][c0 + 2], p3 = pa[ti_][c0 + 3];
      float a0 = s0 * p0, a1 = s1 * p1, a2 = s2 * p2, a3 = s3 * p3;
      float b0 = (1.0f - s0) * p0, b1 = (1.0f - s1) * p1;
      float b2 = (1.0f - s2) * p2, b3 = (1.0f - s3) * p3;
      if (!colstore) {
        unsigned off = ((unsigned)(m * 128 + c0 * 2)) ^
                       ((unsigned)(m & 7) << 4);
        *reinterpret_cast<uint2*>(reinterpret_cast<char*>(S1) + off) =
            make_uint2(pack2(a0, a1), pack2(a2, a3));
        *reinterpret_cast<uint2*>(reinterpret_cast<char*>(S0) + off) =
            make_uint2(pack2(b0, b1), pack2(b2, b3));
      } else {
        float av[4] = {a0, a1, a2, a3}, bv[4] = {b0, b1, b2, b3};
        #pragma unroll
        for (int e = 0; e < 4; ++e) {
          int c = c0 + e;
          unsigned off = ((unsigned)(c * 128 + m * 2)) ^
                         ((unsigned)(c & 7) << 4);
          *reinterpret_cast<unsigned short*>(
              reinterpret_cast<char*>(S1) + off) = bf16b(av[e]);
          *reinterpret_cast<unsigned short*>(
              reinterpret_cast<char*>(S0) + off) = bf16b(bv[e]);
        }
      }
    }
  }
  __syncthreads();

  // ---- phase B: products. g<15: wave does v = 2*wid, 2*wid+1; g==15: v=wid.
  int nv = (g < 15) ? 2 : 1;
  for (int pv = 0; pv < nv; ++pv) {
    int v = (g < 15) ? (2 * wid + pv) : wid;
    short8 A[4][2], B[4][2];
    f32x16 C1[2][2], C2[2][2], C3[2][2];
    char* rb = role[wid];
    if (g < 15) {
      int b0 = v & 1, b1 = (v >> 1) & 1, b2 = (v >> 2) & 1, b3 = (v >> 3) & 1;
      loadA_lds(A, (char*)E[3 * 2 + b3], lo, hi);   // E3^T (col-stored)
      loadB_lds(B, (char*)E[2 * 2 + b2], lo, hi);   // E2^T (row-stored)
      mm64(A, B, C1);                               // (E2E3)^T
      loadA_lds(A, (char*)E[1 * 2 + b1], lo, hi);   // E1^T
      loadB_lds(B, (char*)E[0 * 2 + b0], lo, hi);   // E0^T
      mm64(A, B, C2);                               // (E0E1)^T
      store_role0(C1, rb, lo, hi);   // single wave: ds ops program-ordered
      loadA_lds(A, rb, lo, hi);
      rebuildB(C2, B, hi);
      mm64(A, B, C3);                               // (E0..E3)^T
    } else {
      int b0 = v & 1, b1 = (v >> 1) & 1, b2 = (v >> 2) & 1;
      loadA_lds(A, (char*)E[2 * 2 + b2], lo, hi);   // E62^T (col)
      loadB_lds(B, (char*)E[1 * 2 + b1], lo, hi);   // E61^T (row)
      mm64(A, B, C1);                               // (E61E62)^T
      store_role0(C1, rb, lo, hi);
      loadA_lds(A, rb, lo, hi);
      loadB_lds(B, (char*)E[0 * 2 + b0], lo, hi);   // E60^T (row)
      mm64(A, B, C3);                               // (E60..E62)^T
    }
    int bid_p = (g < 15) ? (g * 16 + v) : (240 + v);
    unsigned short* outp = MqC + (size_t)bid_p * 4096;
    #pragma unroll
    for (int ti = 0; ti < 2; ++ti)
      #pragma unroll
      for (int j = 0; j < 2; ++j)
        #pragma unroll
        for (int r = 0; r < 16; ++r) {
          int m = 32 * ti + (r & 3) + 8 * (r >> 2) + 4 * hi;  // PT row=P col
          int n = 32 * j + lo;                                // PT col=P row
          outp[(m >> 3) * 512 + n * 8 + (m & 7)] = bf16b(C3[ti][j][r]);
        }
  }
}

// ---------------- chain: 16 steps, 4 waves/batch (R8, validated) -----------
__global__ __launch_bounds__(256) void chain_kernel(
    const float* __restrict__ x, const float* __restrict__ theta,
    const unsigned short* __restrict__ MqC, float* __restrict__ out) {
  int b = blockIdx.x;           // 0..511
  int tid = threadIdx.x;
  int w = tid >> 6, l = tid & 63;
  int al = l & 15;              // local row
  int q = l >> 4;               // j-quarter: j in [16q, 16q+16)
  int a = 16 * w + al;          // output row owned by this lane

  unsigned long long mask = __ballot(x[b * 64 + l] != 0.0f);

  __shared__ __align__(16) float ubuf[2][64];

  float th = theta[63 * 4096 + l * 64];
  float sg = 1.0f / (1.0f + __expf(-th));
  float pv = ((mask >> 63) & 1ull) ? sg : (1.0f - sg);
  if (w == 0) ubuf[0][l] = pv;
  __syncthreads();

#define GIDX(g) ((g) < 15 ? (g) * 16 + (int)((mask >> (4 * (g))) & 15ull) \
                          : 240 + (int)((mask >> 60) & 7ull))

  short8 qa[2], qb[2], qc[2];

#define PRE(REG, PG)                                                        \
  {                                                                         \
    const unsigned short* Pb =                                              \
        MqC + (size_t)GIDX(PG) * 4096 + (q * 1024 + a * 8);                 \
    REG[0] = *reinterpret_cast<const short8*>(Pb);                          \
    REG[1] = *reinterpret_cast<const short8*>(Pb + 512);                    \
  }

  float rscale = 1.0f, acc = 0.0f;

#define STEP(QREG, PG, PREG, CUR, DO_RS, LAST)                              \
  {                                                                         \
    if ((PG) >= 0) PRE(PREG, PG);                                           \
    const float* uc = ubuf[CUR];                                            \
    float4 u0 = *(const float4*)&uc[16 * q + 0];                            \
    float4 u1 = *(const float4*)&uc[16 * q + 4];                            \
    float4 u2 = *(const float4*)&uc[16 * q + 8];                            \
    float4 u3 = *(const float4*)&uc[16 * q + 12];                           \
    U8 f0, f1;                                                              \
    f0.v = QREG[0]; f1.v = QREG[1];                                         \
    float s0 = 0.f, s1 = 0.f, s2 = 0.f, s3 = 0.f;                           \
    s0 = fmaf(bfcvt(f0.s[0]), u0.x, s0);                                    \
    s1 = fmaf(bfcvt(f0.s[1]), u0.y, s1);                                    \
    s2 = fmaf(bfcvt(f0.s[2]), u0.z, s2);                                    \
    s3 = fmaf(bfcvt(f0.s[3]), u0.w, s3);                                    \
    s0 = fmaf(bfcvt(f0.s[4]), u1.x, s0);                                    \
    s1 = fmaf(bfcvt(f0.s[5]), u1.y, s1);                                    \
    s2 = fmaf(bfcvt(f0.s[6]), u1.z, s2);                                    \
    s3 = fmaf(bfcvt(f0.s[7]), u1.w, s3);                                    \
    s0 = fmaf(bfcvt(f1.s[0]), u2.x, s0);                                    \
    s1 = fmaf(bfcvt(f1.s[1]), u2.y, s1);                                    \
    s2 = fmaf(bfcvt(f1.s[2]), u2.z, s2);                                    \
    s3 = fmaf(bfcvt(f1.s[3]), u2.w, s3);                                    \
    s0 = fmaf(bfcvt(f1.s[4]), u3.x, s0);                                    \
    s1 = fmaf(bfcvt(f1.s[5]), u3.y, s1);                                    \
    s2 = fmaf(bfcvt(f1.s[6]), u3.z, s2);                                    \
    s3 = fmaf(bfcvt(f1.s[7]), u3.w, s3);                                    \
    float s = (s0 + s1) + (s2 + s3);                                        \
    s += __shfl_xor(s, 16);                                                 \
    s += __shfl_xor(s, 32);                                                 \
    if (DO_RS) s *= rscale;                                                 \
    if (LAST) {                                                             \
      if (q == 0) out[b * 64 + a] = logf(s) + acc;                          \
    } else {                                                                \
      if (q == 0) ubuf[(CUR) ^ 1][a] = s;                                   \
      __syncthreads();                                                      \
    }                                                                       \
  }

  PRE(qa, 15);
  PRE(qb, 14);

  STEP(qa, 13, qc, 0, 0, 0);   // g=15
  STEP(qb, 12, qa, 1, 0, 0);   // g=14
  STEP(qc, 11, qb, 0, 0, 0);   // g=13
  STEP(qa, 10, qc, 1, 0, 0);   // g=12
  STEP(qb,  9, qa, 0, 0, 0);   // g=11
  STEP(qc,  8, qb, 1, 0, 0);   // g=10
  STEP(qa,  7, qc, 0, 0, 0);   // g=9
  STEP(qb,  6, qa, 1, 0, 0);   // g=8  -> u in ubuf[0]

  {  // renorm (same placement as R7/R8)
    float uv = ubuf[0][l];
    float m = uv;
    #pragma unroll
    for (int o = 32; o >= 1; o >>= 1) m = fmaxf(m, __shfl_xor(m, o));
    rscale = 1.0f / m;
    acc = __logf(m);
  }

  STEP(qc,  5, qb, 0, 1, 0);   // g=7, applies rscale
  STEP(qa,  4, qc, 1, 0, 0);   // g=6
  STEP(qb,  3, qa, 0, 0, 0);   // g=5
  STEP(qc,  2, qb, 1, 0, 0);   // g=4
  STEP(qa,  1, qc, 0, 0, 0);   // g=3
  STEP(qb,  0, qa, 1, 0, 0);   // g=2
  STEP(qc, -1, qb, 0, 0, 0);   // g=1
  STEP(qa, -1, qb, 1, 0, 1);   // g=0, write out

#undef STEP
#undef PRE
#undef GIDX
}

extern "C" void kernel_launch(void* const* d_in, const int* in_sizes, int n_in,
                              void* d_out, int out_size, void* d_ws, size_t ws_size,
                              hipStream_t stream) {
  const float* x     = (const float*)d_in[0];  // (512, 64)
  const float* theta = (const float*)d_in[1];  // (1, 64, 64, 64)
  const float* ulpa  = (const float*)d_in[2];  // (1, 63, 1, 64)
  float* out = (float*)d_out;                  // (512, 64, 1)

  unsigned short* MqC = (unsigned short*)d_ws; // 248*4096 bf16 (~2 MB)

  hipLaunchKernelGGL(table_kernel, dim3(16), dim3(512), 0, stream,
                     theta, ulpa, MqC);
  hipLaunchKernelGGL(chain_kernel, dim3(512), dim3(256), 0, stream,
                     x, theta, MqC, out);
}

// Round 11
// 73.702 us; speedup vs baseline: 1.4614x; 1.1542x over previous
//
#include <hip/hip_runtime.h>
#include <hip/hip_bf16.h>

// BATCH=512, INPUT_SIZE=64, ALPHA_DIM=64
// out[b,:] = log( M_0 ... M_62 p ).  Pipeline (R8 configuration — measured
// best, 73.9 us; R9 fusion and R10 consolidation both regressed):
//  e_kernel:    E[t][v] bf16 dual layout (R6-validated).
//  quad_kernel: 248 group products -> bf16 chain layout (R7-validated):
//               P[a][j] at (j>>3)*512 + a*8 + (j&7).
//  chain_kernel: 1 block/batch, 4 waves; per step lane (w,l) owns row
//               a=16w+(l&15), j-quarter q=l>>4; 16-FMA partial +
//               shfl_xor(16,32) fold; ping-pong u in LDS, one barrier/step;
//               2-step-ahead register prefetch; one renorm.

#define NSTEP 63

typedef __attribute__((ext_vector_type(8)))  short short8;
typedef __attribute__((ext_vector_type(16))) float f32x16;

union U8 { short8 v; unsigned u[4]; unsigned short s[8]; };

static __device__ __forceinline__ unsigned short bf16b(float f) {
  union { __hip_bfloat16 h; unsigned short u; } cv;
  cv.h = __float2bfloat16(f);
  return cv.u;
}
static __device__ __forceinline__ unsigned pack2(float a, float b) {
  return (unsigned)bf16b(a) | ((unsigned)bf16b(b) << 16);
}
static __device__ __forceinline__ float bfcvt(unsigned short s) {
  return __uint_as_float((unsigned)s << 16);
}

// ---------------- e_kernel: E tables, dual layout (R6, validated) ----------
__global__ __launch_bounds__(256) void e_kernel(
    const float* __restrict__ theta, const float* __restrict__ ulpa,
    unsigned short* __restrict__ EA, unsigned short* __restrict__ EB) {
  int t = blockIdx.x;          // 0..62
  int tid = threadIdx.x;
  __shared__ float sig[64][65];
  __shared__ float pa[64];

  if (tid < 64) {
    float u = ulpa[t * 64 + tid];
    float m = u;
    #pragma unroll
    for (int o = 32; o >= 1; o >>= 1) m = fmaxf(m, __shfl_xor(m, o));
    float e = __expf(u - m);
    float s = e;
    #pragma unroll
    for (int o = 32; o >= 1; o >>= 1) s += __shfl_xor(s, o);
    pa[tid] = e / s;
  }

  const float4* th4 = (const float4*)(theta + t * 4096);
  #pragma unroll
  for (int k = 0; k < 4; ++k) {
    int i = tid + k * 256;
    float4 v = th4[i];
    int m = i >> 4, n0 = (i & 15) * 4;
    sig[m][n0 + 0] = 1.0f / (1.0f + __expf(-v.x));
    sig[m][n0 + 1] = 1.0f / (1.0f + __expf(-v.y));
    sig[m][n0 + 2] = 1.0f / (1.0f + __expf(-v.z));
    sig[m][n0 + 3] = 1.0f / (1.0f + __expf(-v.w));
  }
  __syncthreads();

  unsigned short* EA0 = EA + (size_t)(t * 2 + 0) * 4096;
  unsigned short* EA1 = EA + (size_t)(t * 2 + 1) * 4096;
  unsigned short* EB0 = EB + (size_t)(t * 2 + 0) * 4096;
  unsigned short* EB1 = EB + (size_t)(t * 2 + 1) * 4096;

  #pragma unroll
  for (int k = 0; k < 4; ++k) {
    int i = tid + k * 256;
    int m = i >> 4, n0 = (i & 15) * 4;
    float p0 = pa[n0], p1 = pa[n0 + 1], p2 = pa[n0 + 2], p3 = pa[n0 + 3];
    float s0 = sig[m][n0], s1 = sig[m][n0 + 1];
    float s2 = sig[m][n0 + 2], s3 = sig[m][n0 + 3];
    *reinterpret_cast<uint2*>(&EA1[m * 64 + n0]) =
        make_uint2(pack2(s0 * p0, s1 * p1), pack2(s2 * p2, s3 * p3));
    *reinterpret_cast<uint2*>(&EA0[m * 64 + n0]) =
        make_uint2(pack2((1.0f - s0) * p0, (1.0f - s1) * p1),
                   pack2((1.0f - s2) * p2, (1.0f - s3) * p3));
  }
  #pragma unroll
  for (int k = 0; k < 4; ++k) {
    int i = tid + k * 256;
    int n = i >> 4, m0 = (i & 15) * 4;
    float pn = pa[n];
    float s0 = sig[m0][n], s1 = sig[m0 + 1][n];
    float s2 = sig[m0 + 2][n], s3 = sig[m0 + 3][n];
    *reinterpret_cast<uint2*>(&EB1[n * 64 + m0]) =
        make_uint2(pack2(s0 * pn, s1 * pn), pack2(s2 * pn, s3 * pn));
    *reinterpret_cast<uint2*>(&EB0[n * 64 + m0]) =
        make_uint2(pack2((1.0f - s0) * pn, (1.0f - s1) * pn),
                   pack2((1.0f - s2) * pn, (1.0f - s3) * pn));
  }
}

// ---------------- shared MFMA helpers (R5/R6-validated) ----------------
static __device__ __forceinline__ void mm64(const short8 A[4][2],
                                            const short8 B[4][2],
                                            f32x16 C[2][2]) {
  #pragma unroll
  for (int ti = 0; ti < 2; ++ti)
    #pragma unroll
    for (int j = 0; j < 2; ++j)
      #pragma unroll
      for (int r = 0; r < 16; ++r) C[ti][j][r] = 0.0f;
  #pragma unroll
  for (int kc = 0; kc < 4; ++kc)
    #pragma unroll
    for (int j = 0; j < 2; ++j)
      #pragma unroll
      for (int ti = 0; ti < 2; ++ti)
        C[ti][j] = __builtin_amdgcn_mfma_f32_32x32x16_bf16(
            A[kc][ti], B[kc][j], C[ti][j], 0, 0, 0);
}

static __device__ __forceinline__ void loadA_g(short8 A[4][2],
                                               const unsigned short* M,
                                               int lo, int hi) {
  #pragma unroll
  for (int kc = 0; kc < 4; ++kc)
    #pragma unroll
    for (int ti = 0; ti < 2; ++ti)
      A[kc][ti] = *reinterpret_cast<const short8*>(
          &M[(32 * ti + lo) * 64 + 16 * kc + 8 * hi]);
}
static __device__ __forceinline__ void loadB_g(short8 B[4][2],
                                               const unsigned short* M,
                                               int lo, int hi) {
  #pragma unroll
  for (int kc = 0; kc < 4; ++kc)
    #pragma unroll
    for (int j = 0; j < 2; ++j)
      B[kc][j] = *reinterpret_cast<const short8*>(
          &M[(32 * j + lo) * 64 + 16 * kc + 8 * hi]);
}

// LDS role-0 buffer, bf16, XOR-swizzled: byte ^= (row&7)<<4
static __device__ __forceinline__ void store_role0(const f32x16 C[2][2],
                                                   char* base, int lo, int hi) {
  #pragma unroll
  for (int ti = 0; ti < 2; ++ti)
    #pragma unroll
    for (int j = 0; j < 2; ++j)
      #pragma unroll
      for (int r = 0; r < 16; ++r) {
        int m = 32 * ti + (r & 3) + 8 * (r >> 2) + 4 * hi;
        int n = 32 * j + lo;
        unsigned byteoff =
            ((unsigned)(m * 128 + n * 2)) ^ ((unsigned)(m & 7) << 4);
        *reinterpret_cast<unsigned short*>(base + byteoff) = bf16b(C[ti][j][r]);
      }
}

static __device__ __forceinline__ void loadA_lds(short8 A[4][2],
                                                 const char* base,
                                                 int lo, int hi) {
  #pragma unroll
  for (int kc = 0; kc < 4; ++kc)
    #pragma unroll
    for (int ti = 0; ti < 2; ++ti) {
      int m = 32 * ti + lo;
      unsigned byteoff = ((unsigned)(m * 128 + (16 * kc + 8 * hi) * 2)) ^
                         ((unsigned)(m & 7) << 4);
      A[kc][ti] = *reinterpret_cast<const short8*>(base + byteoff);
    }
}

// C regs -> B-frags of same matrix (validated lane^32 parity exchange)
static __device__ __forceinline__ void rebuildB(const f32x16 C[2][2],
                                                short8 B[4][2], int hi) {
  #pragma unroll
  for (int kc = 0; kc < 4; ++kc) {
    int Me = 2 * kc, Mo = 2 * kc + 1;
    int tie = Me >> 2, me = Me & 3;
    int tio = Mo >> 2, mo = Mo & 3;
    #pragma unroll
    for (int j = 0; j < 2; ++j) {
      unsigned pe0 = pack2(C[tie][j][4 * me + 0], C[tie][j][4 * me + 1]);
      unsigned pe1 = pack2(C[tie][j][4 * me + 2], C[tie][j][4 * me + 3]);
      unsigned po0 = pack2(C[tio][j][4 * mo + 0], C[tio][j][4 * mo + 1]);
      unsigned po1 = pack2(C[tio][j][4 * mo + 2], C[tio][j][4 * mo + 3]);
      unsigned s0 = hi ? pe0 : po0;
      unsigned s1 = hi ? pe1 : po1;
      unsigned r0 = (unsigned)__shfl_xor((int)s0, 32);
      unsigned r1 = (unsigned)__shfl_xor((int)s1, 32);
      U8 f;
      f.u[0] = hi ? r0 : pe0;
      f.u[1] = hi ? r1 : pe1;
      f.u[2] = hi ? po0 : r0;
      f.u[3] = hi ? po1 : r1;
      B[kc][j] = f.v;
    }
  }
}

// ---------------- quad_kernel: group products, depth-2 (R7, validated) -----
__global__ __launch_bounds__(64) void quad_kernel(
    const unsigned short* __restrict__ EA, const unsigned short* __restrict__ EB,
    unsigned short* __restrict__ MqC) {
  __shared__ __align__(16) char Lsh[8192];

  int bid = blockIdx.x;
  int lane = threadIdx.x, lo = lane & 31, hi = lane >> 5;
  int v, nt, t0;
  if (bid < 240) { v = bid & 15; nt = 4; t0 = 4 * (bid >> 4); }
  else           { v = bid - 240; nt = 3; t0 = 60; }

  short8 A[4][2], B[4][2];
  f32x16 C1[2][2], C2[2][2], C3[2][2];

  if (nt == 4) {
    int b0 = v & 1, b1 = (v >> 1) & 1, b2 = (v >> 2) & 1, b3 = (v >> 3) & 1;
    loadA_g(A, EB + (size_t)((t0 + 3) * 2 + b3) * 4096, lo, hi);  // E3^T
    loadB_g(B, EA + (size_t)((t0 + 2) * 2 + b2) * 4096, lo, hi);  // E2^T
    mm64(A, B, C1);                                               // (E2E3)^T
    loadA_g(A, EB + (size_t)((t0 + 1) * 2 + b1) * 4096, lo, hi);  // E1^T
    loadB_g(B, EA + (size_t)((t0 + 0) * 2 + b0) * 4096, lo, hi);  // E0^T
    mm64(A, B, C2);                                               // (E0E1)^T
    store_role0(C1, Lsh, lo, hi);   // single wave: ds ops program-ordered
    loadA_lds(A, Lsh, lo, hi);
    rebuildB(C2, B, hi);
    mm64(A, B, C3);                 // (E0E1E2E3)^T
  } else {
    int b0 = v & 1, b1 = (v >> 1) & 1, b2 = (v >> 2) & 1;
    loadA_g(A, EB + (size_t)((t0 + 2) * 2 + b2) * 4096, lo, hi);
    loadB_g(B, EA + (size_t)((t0 + 1) * 2 + b1) * 4096, lo, hi);
    mm64(A, B, C1);                                               // (E61E62)^T
    store_role0(C1, Lsh, lo, hi);
    loadA_lds(A, Lsh, lo, hi);
    loadB_g(B, EA + (size_t)((t0 + 0) * 2 + b0) * 4096, lo, hi);  // E60^T
    mm64(A, B, C3);                                               // (E60..E62)^T
  }

  unsigned short* outp = MqC + (size_t)bid * 4096;
  #pragma unroll
  for (int ti = 0; ti < 2; ++ti)
    #pragma unroll
    for (int j = 0; j < 2; ++j)
      #pragma unroll
      for (int r = 0; r < 16; ++r) {
        int m = 32 * ti + (r & 3) + 8 * (r >> 2) + 4 * hi;   // PT row = P col
        int n = 32 * j + lo;                                 // PT col = P row
        outp[(m >> 3) * 512 + n * 8 + (m & 7)] = bf16b(C3[ti][j][r]);
      }
}

// ---------------- chain: 16 steps, 4 waves/batch, split matvec -------------
__global__ __launch_bounds__(256) void chain_kernel(
    const float* __restrict__ x, const float* __restrict__ theta,
    const unsigned short* __restrict__ MqC, float* __restrict__ out) {
  int b = blockIdx.x;           // 0..511
  int tid = threadIdx.x;
  int w = tid >> 6, l = tid & 63;
  int al = l & 15;              // local row
  int q = l >> 4;               // j-quarter: j in [16q, 16q+16)
  int a = 16 * w + al;          // output row owned by this lane

  // each wave independently computes the same 64-bit mask
  unsigned long long mask = __ballot(x[b * 64 + l] != 0.0f);

  __shared__ __align__(16) float ubuf[2][64];

  // init u = p (sigma variant of theta[63][l][0]); wave 0 writes buf 0
  float th = theta[63 * 4096 + l * 64];
  float sg = 1.0f / (1.0f + __expf(-th));
  float pv = ((mask >> 63) & 1ull) ? sg : (1.0f - sg);
  if (w == 0) ubuf[0][l] = pv;
  __syncthreads();

#define GIDX(g) ((g) < 15 ? (g) * 16 + (int)((mask >> (4 * (g))) & 15ull) \
                          : 240 + (int)((mask >> 60) & 7ull))

  // per-lane table frags: P[a][16q+e] (frag0) and P[a][16q+8+e] (frag1)
  short8 qa[2], qb[2], qc[2];

#define PRE(REG, PG)                                                        \
  {                                                                         \
    const unsigned short* Pb =                                              \
        MqC + (size_t)GIDX(PG) * 4096 + (q * 1024 + a * 8);                 \
    REG[0] = *reinterpret_cast<const short8*>(Pb);                          \
    REG[1] = *reinterpret_cast<const short8*>(Pb + 512);                    \
  }

  float rscale = 1.0f, acc = 0.0f;

  // One step: read u quarter (broadcast within 16-lane group), 16 FMAs,
  // fold partials across q via shfl_xor(16,32), q==0 lanes write u_new to
  // the other buffer, barrier.  LAST: write out directly, no barrier.
#define STEP(QREG, PG, PREG, CUR, DO_RS, LAST)                              \
  {                                                                         \
    if ((PG) >= 0) PRE(PREG, PG);                                           \
    const float* uc = ubuf[CUR];                                            \
    float4 u0 = *(const float4*)&uc[16 * q + 0];                            \
    float4 u1 = *(const float4*)&uc[16 * q + 4];                            \
    float4 u2 = *(const float4*)&uc[16 * q + 8];                            \
    float4 u3 = *(const float4*)&uc[16 * q + 12];                           \
    U8 f0, f1;                                                              \
    f0.v = QREG[0]; f1.v = QREG[1];                                         \
    float s0 = 0.f, s1 = 0.f, s2 = 0.f, s3 = 0.f;                           \
    s0 = fmaf(bfcvt(f0.s[0]), u0.x, s0);                                    \
    s1 = fmaf(bfcvt(f0.s[1]), u0.y, s1);                                    \
    s2 = fmaf(bfcvt(f0.s[2]), u0.z, s2);                                    \
    s3 = fmaf(bfcvt(f0.s[3]), u0.w, s3);                                    \
    s0 = fmaf(bfcvt(f0.s[4]), u1.x, s0);                                    \
    s1 = fmaf(bfcvt(f0.s[5]), u1.y, s1);                                    \
    s2 = fmaf(bfcvt(f0.s[6]), u1.z, s2);                                    \
    s3 = fmaf(bfcvt(f0.s[7]), u1.w, s3);                                    \
    s0 = fmaf(bfcvt(f1.s[0]), u2.x, s0);                                    \
    s1 = fmaf(bfcvt(f1.s[1]), u2.y, s1);                                    \
    s2 = fmaf(bfcvt(f1.s[2]), u2.z, s2);                                    \
    s3 = fmaf(bfcvt(f1.s[3]), u2.w, s3);                                    \
    s0 = fmaf(bfcvt(f1.s[4]), u3.x, s0);                                    \
    s1 = fmaf(bfcvt(f1.s[5]), u3.y, s1);                                    \
    s2 = fmaf(bfcvt(f1.s[6]), u3.z, s2);                                    \
    s3 = fmaf(bfcvt(f1.s[7]), u3.w, s3);                                    \
    float s = (s0 + s1) + (s2 + s3);                                        \
    s += __shfl_xor(s, 16);                                                 \
    s += __shfl_xor(s, 32);                                                 \
    if (DO_RS) s *= rscale;                                                 \
    if (LAST) {                                                             \
      if (q == 0) out[b * 64 + a] = logf(s) + acc;                          \
    } else {                                                                \
      if (q == 0) ubuf[(CUR) ^ 1][a] = s;                                   \
      __syncthreads();                                                      \
    }                                                                       \
  }

  PRE(qa, 15);
  PRE(qb, 14);

  STEP(qa, 13, qc, 0, 0, 0);   // g=15
  STEP(qb, 12, qa, 1, 0, 0);   // g=14
  STEP(qc, 11, qb, 0, 0, 0);   // g=13
  STEP(qa, 10, qc, 1, 0, 0);   // g=12
  STEP(qb,  9, qa, 0, 0, 0);   // g=11
  STEP(qc,  8, qb, 1, 0, 0);   // g=10
  STEP(qa,  7, qc, 0, 0, 0);   // g=9
  STEP(qb,  6, qa, 1, 0, 0);   // g=8  -> u in ubuf[0]

  {  // renorm (same placement as R7: after 8 group-steps = 32 t's)
    float uv = ubuf[0][l];
    float m = uv;
    #pragma unroll
    for (int o = 32; o >= 1; o >>= 1) m = fmaxf(m, __shfl_xor(m, o));
    rscale = 1.0f / m;
    acc = __logf(m);
    // reads only; ubuf[0] was written+barriered, next step reads it again
  }

  STEP(qc,  5, qb, 0, 1, 0);   // g=7, applies rscale
  STEP(qa,  4, qc, 1, 0, 0);   // g=6
  STEP(qb,  3, qa, 0, 0, 0);   // g=5
  STEP(qc,  2, qb, 1, 0, 0);   // g=4
  STEP(qa,  1, qc, 0, 0, 0);   // g=3
  STEP(qb,  0, qa, 1, 0, 0);   // g=2
  STEP(qc, -1, qb, 0, 0, 0);   // g=1
  STEP(qa, -1, qb, 1, 0, 1);   // g=0, write out

#undef STEP
#undef PRE
#undef GIDX
}

extern "C" void kernel_launch(void* const* d_in, const int* in_sizes, int n_in,
                              void* d_out, int out_size, void* d_ws, size_t ws_size,
                              hipStream_t stream) {
  const float* x     = (const float*)d_in[0];  // (512, 64)
  const float* theta = (const float*)d_in[1];  // (1, 64, 64, 64)
  const float* ulpa  = (const float*)d_in[2];  // (1, 63, 1, 64)
  float* out = (float*)d_out;                  // (512, 64, 1)

  unsigned short* MqC = (unsigned short*)d_ws;             // 248*4096 bf16
  unsigned short* EA  = MqC + (size_t)248 * 4096;          // 63*2*4096 bf16
  unsigned short* EB  = EA + (size_t)NSTEP * 2 * 4096;     // 63*2*4096 bf16

  hipLaunchKernelGGL(e_kernel, dim3(NSTEP), dim3(256), 0, stream,
                     theta, ulpa, EA, EB);
  hipLaunchKernelGGL(quad_kernel, dim3(248), dim3(64), 0, stream,
                     EA, EB, MqC);
  hipLaunchKernelGGL(chain_kernel, dim3(512), dim3(256), 0, stream,
                     x, theta, MqC, out);
}